// Round 7
// baseline (206.243 us; speedup 1.0000x reference)
//
#include <hip/hip_runtime.h>
#include <hip/hip_bf16.h>

// TurboQuantMSE: x_hat = Q(x @ R^T) @ R, Q = 16-level Lloyd-Max quantizer.
// fp16 MFMA GEMMs. Round 7: 128x128 tile, 4 waves, grid 512 -> 2 RESIDENT
// blocks/CU (R3-R6 all ran 1 block/CU = one barrier gang, sync-bound at
// ~83us/GEMM with nothing saturated). Cross-block overlap per SIMD is the
// m97/m114 mechanism. Keeps R6's proven pieces: BK=32, 3-buffer LDS (48KB),
// counted vmcnt(4) boundary, conflict-free swizzle, setprio, 1 barrier/tile.

typedef __attribute__((ext_vector_type(8))) _Float16 f16x8;
typedef __attribute__((ext_vector_type(4))) float f32x4;

__device__ __forceinline__ unsigned short f2h(float f) {
    _Float16 h = (_Float16)f;
    return *reinterpret_cast<unsigned short*>(&h);
}

// ---------------- elementwise f32 -> fp16 (x) ----------------
__global__ __launch_bounds__(256) void convert_x_kernel(
    const float* __restrict__ x, unsigned short* __restrict__ xb) {
    const int i = (blockIdx.x * 256 + threadIdx.x) * 4;
    float4 v = *reinterpret_cast<const float4*>(x + i);
    ushort4 b;
    b.x = f2h(v.x); b.y = f2h(v.y); b.z = f2h(v.z); b.w = f2h(v.w);
    *reinterpret_cast<ushort4*>(xb + i) = b;
}

// ---------------- rotation f32 -> fp16 (row-major) + fp16 transposed --------
__global__ __launch_bounds__(256) void conv_rot_kernel(
    const float* __restrict__ R, unsigned short* __restrict__ Rb,
    unsigned short* __restrict__ Rt) {
    __shared__ float t[64][65];
    const int tid = threadIdx.x;
    const int tr = blockIdx.y * 64, tc = blockIdx.x * 64;
    const int r0 = tid >> 4;
    const int c4 = (tid & 15) << 2;
#pragma unroll
    for (int i = 0; i < 4; i++) {
        const int r = r0 + i * 16;
        float4 v = *reinterpret_cast<const float4*>(
            &R[(size_t)(tr + r) * 4096 + tc + c4]);
        ushort4 b;
        b.x = f2h(v.x); b.y = f2h(v.y); b.z = f2h(v.z); b.w = f2h(v.w);
        *reinterpret_cast<ushort4*>(&Rb[(size_t)(tr + r) * 4096 + tc + c4]) = b;
        t[r][c4 + 0] = v.x; t[r][c4 + 1] = v.y;
        t[r][c4 + 2] = v.z; t[r][c4 + 3] = v.w;
    }
    __syncthreads();
#pragma unroll
    for (int i = 0; i < 16; i++) {
        const int idx = tid + 256 * i;
        const int rr = idx >> 6;
        const int cc = idx & 63;
        Rt[(size_t)(tc + rr) * 4096 + tr + cc] = f2h(t[cc][rr]);
    }
}

// ---------------- pipelined NT GEMM -----------------------------------------
// C[2048,4096] = A[2048,K] * Bt[4096,K]^T, fp16 in, f32 accum.
// BM=BN=128, BK=32, 4 waves (2M x 2N), per-wave 64x64 (4x4 frags).
// LDS rows 64B. A region 8KB + B region 8KB = 16KB/buffer, 3 buffers = 48KB
// -> 2 blocks/CU. 4 staging chunks/tile (A:2, B:2), staged 2 tiles ahead.
// Per tile: {8 ds_read | stage(t+2)x4 | lgkmcnt(0) | 16 MFMA | vmcnt(4) | bar}
constexpr int GK = 4096;
constexpr int BM = 128, BN = 128, BK = 32;
constexpr int NT = GK / BK;                 // 128
constexpr int A_LDS = BM * BK * 2;          // 8192
constexpr int BUF = (BM + BN) * BK * 2;     // 16384
constexpr int LDS_DYN = 3 * BUF;            // 49152

template <bool QUANT>
__global__ __launch_bounds__(256, 2) void gemm_nt_kernel(
    const unsigned short* __restrict__ A, const unsigned short* __restrict__ Bt,
    void* __restrict__ Cout, const float* __restrict__ cb16) {
    extern __shared__ char smem[];
    const int tid = threadIdx.x;
    const int lane = tid & 63;
    const int w = tid >> 6;        // 0..3
    const int wm = w >> 1;         // 0..1
    const int wn = w & 1;          // 0..1

    // XCD-aware bijective swizzle (512 blocks, 512%8==0)
    const int bid = blockIdx.x;
    const int wgid = (bid & 7) * 64 + (bid >> 3);
    const int tn = wgid & 31;      // N/BN = 32
    const int tm = wgid >> 5;      // M/BM = 16

    f32x4 acc[4][4];
#pragma unroll
    for (int m = 0; m < 4; m++)
#pragma unroll
        for (int n = 0; n < 4; n++) acc[m][n] = (f32x4){0.f, 0.f, 0.f, 0.f};

    // ---- staging: 4 chunks of 4KB (64 rows x 64B each). thread: row=tid>>2,
    // slot=tid&3; LDS dst is linear tid*16; global col pre-swizzled so
    // linear dst + swizzled read agree (swizzle: slot ^= (row>>1)&3).
    const int srow = tid >> 2;                                  // 0..63
    const int scol = (((tid & 3) ^ ((srow >> 1) & 3)) << 3);    // elements
    const unsigned short* ApS0 = A + (size_t)(tm * BM + srow) * GK + scol;
    const unsigned short* ApS1 = ApS0 + (size_t)64 * GK;
    const unsigned short* BpS0 = Bt + (size_t)(tn * BN + srow) * GK + scol;
    const unsigned short* BpS1 = BpS0 + (size_t)64 * GK;
    const int tbase = tid << 4;                                 // tid*16 B

#define STAGE(dstbase)                                                         \
    {                                                                          \
        __builtin_amdgcn_global_load_lds(                                      \
            (const __attribute__((address_space(1))) void*)ApS0,               \
            (__attribute__((address_space(3))) void*)(smem + (dstbase) + tbase), 16, 0, 0); \
        __builtin_amdgcn_global_load_lds(                                      \
            (const __attribute__((address_space(1))) void*)ApS1,               \
            (__attribute__((address_space(3))) void*)(smem + (dstbase) + 4096 + tbase), 16, 0, 0); \
        __builtin_amdgcn_global_load_lds(                                      \
            (const __attribute__((address_space(1))) void*)BpS0,               \
            (__attribute__((address_space(3))) void*)(smem + (dstbase) + 8192 + tbase), 16, 0, 0); \
        __builtin_amdgcn_global_load_lds(                                      \
            (const __attribute__((address_space(1))) void*)BpS1,               \
            (__attribute__((address_space(3))) void*)(smem + (dstbase) + 12288 + tbase), 16, 0, 0); \
        ApS0 += BK; ApS1 += BK; BpS0 += BK; BpS1 += BK;                        \
    }

    // ---- fragment read addressing (swizzled): byte = row*64 + swslot*16 ----
    const int sw = (((lane >> 4) ^ (((lane & 15) >> 1) & 3)) << 4);
    const int arow = (wm * 64 + (lane & 15)) * 64;              // A row byte
    const int brow = A_LDS + (wn * 64 + (lane & 15)) * 64;      // B row byte

#define LDA(m) (*reinterpret_cast<const f16x8*>(smem + lb + arow + (m) * 1024 + sw))
#define LDB(n) (*reinterpret_cast<const f16x8*>(smem + lb + brow + (n) * 1024 + sw))
#define MFMA_ROW(aR, r)                                                          \
    acc[r][0] = __builtin_amdgcn_mfma_f32_16x16x32_f16(aR, b0, acc[r][0], 0, 0, 0); \
    acc[r][1] = __builtin_amdgcn_mfma_f32_16x16x32_f16(aR, b1, acc[r][1], 0, 0, 0); \
    acc[r][2] = __builtin_amdgcn_mfma_f32_16x16x32_f16(aR, b2, acc[r][2], 0, 0, 0); \
    acc[r][3] = __builtin_amdgcn_mfma_f32_16x16x32_f16(aR, b3, acc[r][3], 0, 0, 0);

    // ---- prologue: stage tile0 -> buf0, tile1 -> buf1; wait own tile0 ----
    STAGE(0)
    STAGE(BUF)
    asm volatile("s_waitcnt vmcnt(4)" ::: "memory");
    __builtin_amdgcn_s_barrier();
    __builtin_amdgcn_sched_barrier(0);

    int lb = 0;            // buffer holding tile t
    int wb = 2 * BUF;      // buffer receiving tile t+2
    for (int t = 0; t < NT; ++t) {
        f16x8 a0, a1, a2, a3, b0, b1, b2, b3;
        a0 = LDA(0); a1 = LDA(1); a2 = LDA(2); a3 = LDA(3);
        b0 = LDB(0); b1 = LDB(1); b2 = LDB(2); b3 = LDB(3);
        if (t + 2 < NT) STAGE(wb)
        asm volatile("s_waitcnt lgkmcnt(0)" ::: "memory");
        __builtin_amdgcn_sched_barrier(0);
        __builtin_amdgcn_s_setprio(1);
        MFMA_ROW(a0, 0) MFMA_ROW(a1, 1) MFMA_ROW(a2, 2) MFMA_ROW(a3, 3)
        __builtin_amdgcn_s_setprio(0);
        // boundary: ensure tile t+1's chunks (all waves) landed
        if (t + 1 < NT) {
            if (t + 2 < NT) {
                asm volatile("s_waitcnt vmcnt(4)" ::: "memory");
            } else {
                asm volatile("s_waitcnt vmcnt(0)" ::: "memory");
            }
            __builtin_amdgcn_s_barrier();
            __builtin_amdgcn_sched_barrier(0);
            lb = (lb == 2 * BUF) ? 0 : lb + BUF;
            wb = (wb == 2 * BUF) ? 0 : wb + BUF;
        }
    }
#undef LDA
#undef LDB
#undef MFMA_ROW
#undef STAGE

    // ---- epilogue: C/D layout col=lane&15, row=(lane>>4)*4+j ----
    const int crow0 = tm * BM + wm * 64 + ((lane >> 4) << 2);
    const int ccol0 = tn * BN + wn * 64 + (lane & 15);
    if constexpr (QUANT) {
        float c[16];
#pragma unroll
        for (int i = 0; i < 16; i++) c[i] = cb16[i];
        unsigned short* O = (unsigned short*)Cout;
#pragma unroll
        for (int m = 0; m < 4; m++)
#pragma unroll
            for (int n = 0; n < 4; n++)
#pragma unroll
                for (int j = 0; j < 4; j++) {
                    const float yn = acc[m][n][j] * 64.0f;
                    float v = c[0];
#pragma unroll
                    for (int i = 0; i < 15; i++) {
                        const float bnd = 0.5f * (c[i] + c[i + 1]);
                        v = (yn > bnd) ? c[i + 1] : v;
                    }
                    O[(size_t)(crow0 + m * 16 + j) * 4096 + ccol0 + n * 16] =
                        f2h(v * 0.015625f);
                }
    } else {
        float* O = (float*)Cout;
#pragma unroll
        for (int m = 0; m < 4; m++)
#pragma unroll
            for (int n = 0; n < 4; n++)
#pragma unroll
                for (int j = 0; j < 4; j++)
                    O[(size_t)(crow0 + m * 16 + j) * 4096 + ccol0 + n * 16] =
                        acc[m][n][j];
    }
}

extern "C" void kernel_launch(void* const* d_in, const int* in_sizes, int n_in,
                              void* d_out, int out_size, void* d_ws,
                              size_t ws_size, hipStream_t stream) {
    const float* x = (const float*)d_in[0];
    const float* rot = (const float*)d_in[1];
    const float* cb = (const float*)d_in[2];
    float* out = (float*)d_out;

    unsigned short* Xh = (unsigned short*)d_ws;
    unsigned short* Rh = Xh + (size_t)2048 * 4096;
    unsigned short* Rt = Rh + (size_t)4096 * 4096;
    unsigned short* Yh = Rt + (size_t)4096 * 4096;

    (void)hipFuncSetAttribute(
        reinterpret_cast<const void*>(&gemm_nt_kernel<true>),
        hipFuncAttributeMaxDynamicSharedMemorySize, LDS_DYN);
    (void)hipFuncSetAttribute(
        reinterpret_cast<const void*>(&gemm_nt_kernel<false>),
        hipFuncAttributeMaxDynamicSharedMemorySize, LDS_DYN);

    convert_x_kernel<<<8192, 256, 0, stream>>>(x, Xh);
    conv_rot_kernel<<<dim3(64, 64), 256, 0, stream>>>(rot, Rh, Rt);
    // y = x @ R^T : NT GEMM, Bt = Rh
    gemm_nt_kernel<true><<<512, 256, LDS_DYN, stream>>>(Xh, Rh, (void*)Yh, cb);
    // x_hat = y_hat @ R = y_hat @ (R^T)^T : NT GEMM, Bt = Rt
    gemm_nt_kernel<false><<<512, 256, LDS_DYN, stream>>>(Yh, Rt, (void*)out, nullptr);
}

// Round 8
// 180.247 us; speedup vs baseline: 1.1442x; 1.1442x over previous
//
#include <hip/hip_runtime.h>
#include <hip/hip_bf16.h>

// TurboQuantMSE: x_hat = Q(x @ R^T) @ R, Q = 16-level Lloyd-Max quantizer.
// fp16 MFMA GEMMs, 128x256 tile, BK=32, 8 waves (64x64 each), grid 256.
// Round 8: REGISTER-FRAGMENT DOUBLE BUFFER — per tile t, issue ds_reads for
// t+1 while MFMA'ing t from regs; 4 LDS buffers (96KB), 3-tile stage lead.
// All waits counted (lgkmcnt(8), vmcnt(3)), ONE barrier/tile, no drains in
// steady state. Attacks R6's measured gap (83us vs ~51us LDS-port floor):
// reads and MFMA now overlap on separate pipes instead of serializing.

typedef __attribute__((ext_vector_type(8))) _Float16 f16x8;
typedef __attribute__((ext_vector_type(4))) float f32x4;

__device__ __forceinline__ unsigned short f2h(float f) {
    _Float16 h = (_Float16)f;
    return *reinterpret_cast<unsigned short*>(&h);
}

// ---------------- elementwise f32 -> fp16 (x) ----------------
__global__ __launch_bounds__(256) void convert_x_kernel(
    const float* __restrict__ x, unsigned short* __restrict__ xb) {
    const int i = (blockIdx.x * 256 + threadIdx.x) * 4;
    float4 v = *reinterpret_cast<const float4*>(x + i);
    ushort4 b;
    b.x = f2h(v.x); b.y = f2h(v.y); b.z = f2h(v.z); b.w = f2h(v.w);
    *reinterpret_cast<ushort4*>(xb + i) = b;
}

// ---------------- rotation f32 -> fp16 (row-major) + fp16 transposed --------
__global__ __launch_bounds__(256) void conv_rot_kernel(
    const float* __restrict__ R, unsigned short* __restrict__ Rb,
    unsigned short* __restrict__ Rt) {
    __shared__ float t[64][65];
    const int tid = threadIdx.x;
    const int tr = blockIdx.y * 64, tc = blockIdx.x * 64;
    const int r0 = tid >> 4;
    const int c4 = (tid & 15) << 2;
#pragma unroll
    for (int i = 0; i < 4; i++) {
        const int r = r0 + i * 16;
        float4 v = *reinterpret_cast<const float4*>(
            &R[(size_t)(tr + r) * 4096 + tc + c4]);
        ushort4 b;
        b.x = f2h(v.x); b.y = f2h(v.y); b.z = f2h(v.z); b.w = f2h(v.w);
        *reinterpret_cast<ushort4*>(&Rb[(size_t)(tr + r) * 4096 + tc + c4]) = b;
        t[r][c4 + 0] = v.x; t[r][c4 + 1] = v.y;
        t[r][c4 + 2] = v.z; t[r][c4 + 3] = v.w;
    }
    __syncthreads();
#pragma unroll
    for (int i = 0; i < 16; i++) {
        const int idx = tid + 256 * i;
        const int rr = idx >> 6;
        const int cc = idx & 63;
        Rt[(size_t)(tc + rr) * 4096 + tr + cc] = f2h(t[cc][rr]);
    }
}

// ---------------- pipelined NT GEMM, reg-dbuf fragments ---------------------
// C[2048,4096] = A[2048,K] * Bt[4096,K]^T, fp16 in, f32 accum.
// BM=128 BN=256 BK=32, 8 waves (2M x 4N), per-wave 64x64 (4x4 frags).
// LDS rows 64B. Buffer = A 8KB + B 16KB = 24KB; 4 buffers = 96KB.
// 3 stage chunks/tile (A:1, B:2), 3-tile lead. Per tile t:
//  [A] 8 ds_read frags(t+1) from buf (t+1)&3   (overlaps MFMA below)
//  [B] stage(t+3) -> buf (t+3)&3
//  [C] lgkmcnt(8)  — waits only tile t's reads (issued last iter)
//  [D] 16 MFMA on regs(t)
//  [E] vmcnt(3)    — tile t+2's staging landed (own); barrier publishes all
//  [F] s_barrier
constexpr int GK = 4096;
constexpr int BM = 128, BN = 256, BK = 32;
constexpr int NT = GK / BK;                 // 128
constexpr int A_LDS = BM * BK * 2;          // 8192
constexpr int BUF = (BM + BN) * BK * 2;     // 24576
constexpr int LDS_DYN = 4 * BUF;            // 98304

template <bool QUANT>
__global__ __launch_bounds__(512, 2) void gemm_nt_kernel(
    const unsigned short* __restrict__ A, const unsigned short* __restrict__ Bt,
    void* __restrict__ Cout, const float* __restrict__ cb16) {
    extern __shared__ char smem[];
    const int tid = threadIdx.x;
    const int lane = tid & 63;
    const int w = tid >> 6;        // 0..7
    const int wm = w >> 2;         // 0..1
    const int wn = w & 3;          // 0..3

    // XCD-aware bijective swizzle (256 blocks, 256%8==0)
    const int bid = blockIdx.x;
    const int wgid = (bid & 7) * 32 + (bid >> 3);
    const int tn = wgid & 15;      // N/BN = 16
    const int tm = wgid >> 4;      // M/BM = 16

    f32x4 acc[4][4];
#pragma unroll
    for (int m = 0; m < 4; m++)
#pragma unroll
        for (int n = 0; n < 4; n++) acc[m][n] = (f32x4){0.f, 0.f, 0.f, 0.f};

    // ---- staging: 3 chunks of 8KB (128 rows x 64B). row=tid>>2, slot=tid&3;
    // global col pre-swizzled (slot ^= (row>>1)&3) so linear LDS dst +
    // swizzled read agree. gload_lds dst = wave-uniform base (+lane*16 by HW).
    const int srow = tid >> 2;                                  // 0..127
    const int scol = (((tid & 3) ^ ((srow >> 1) & 3)) << 3);    // elements
    const unsigned short* ApS = A + (size_t)(tm * BM + srow) * GK + scol;
    const unsigned short* BpS0 = Bt + (size_t)(tn * BN + srow) * GK + scol;
    const unsigned short* BpS1 = BpS0 + (size_t)128 * GK;
    const int wbase = (w << 10);                                // w*1024 B

#define STAGE(dstbase)                                                         \
    {                                                                          \
        __builtin_amdgcn_global_load_lds(                                      \
            (const __attribute__((address_space(1))) void*)ApS,                \
            (__attribute__((address_space(3))) void*)(smem + (dstbase) + wbase), 16, 0, 0); \
        __builtin_amdgcn_global_load_lds(                                      \
            (const __attribute__((address_space(1))) void*)BpS0,               \
            (__attribute__((address_space(3))) void*)(smem + (dstbase) + A_LDS + wbase), 16, 0, 0); \
        __builtin_amdgcn_global_load_lds(                                      \
            (const __attribute__((address_space(1))) void*)BpS1,               \
            (__attribute__((address_space(3))) void*)(smem + (dstbase) + A_LDS + 8192 + wbase), 16, 0, 0); \
        ApS += BK; BpS0 += BK; BpS1 += BK;                                     \
    }

    // ---- fragment read addressing (swizzled): byte = row*64 + swslot*16 ----
    const int sw = (((lane >> 4) ^ (((lane & 15) >> 1) & 3)) << 4);
    const int arow = (wm * 64 + (lane & 15)) * 64;              // A row byte
    const int brow = A_LDS + (wn * 64 + (lane & 15)) * 64;      // B row byte

#define LDA(rb, m) (*reinterpret_cast<const f16x8*>(smem + (rb) + arow + (m) * 1024 + sw))
#define LDB(rb, n) (*reinterpret_cast<const f16x8*>(smem + (rb) + brow + (n) * 1024 + sw))
#define MFMA_ALL(P)                                                               \
    acc[0][0] = __builtin_amdgcn_mfma_f32_16x16x32_f16(P##a0, P##b0, acc[0][0], 0, 0, 0); \
    acc[0][1] = __builtin_amdgcn_mfma_f32_16x16x32_f16(P##a0, P##b1, acc[0][1], 0, 0, 0); \
    acc[0][2] = __builtin_amdgcn_mfma_f32_16x16x32_f16(P##a0, P##b2, acc[0][2], 0, 0, 0); \
    acc[0][3] = __builtin_amdgcn_mfma_f32_16x16x32_f16(P##a0, P##b3, acc[0][3], 0, 0, 0); \
    acc[1][0] = __builtin_amdgcn_mfma_f32_16x16x32_f16(P##a1, P##b0, acc[1][0], 0, 0, 0); \
    acc[1][1] = __builtin_amdgcn_mfma_f32_16x16x32_f16(P##a1, P##b1, acc[1][1], 0, 0, 0); \
    acc[1][2] = __builtin_amdgcn_mfma_f32_16x16x32_f16(P##a1, P##b2, acc[1][2], 0, 0, 0); \
    acc[1][3] = __builtin_amdgcn_mfma_f32_16x16x32_f16(P##a1, P##b3, acc[1][3], 0, 0, 0); \
    acc[2][0] = __builtin_amdgcn_mfma_f32_16x16x32_f16(P##a2, P##b0, acc[2][0], 0, 0, 0); \
    acc[2][1] = __builtin_amdgcn_mfma_f32_16x16x32_f16(P##a2, P##b1, acc[2][1], 0, 0, 0); \
    acc[2][2] = __builtin_amdgcn_mfma_f32_16x16x32_f16(P##a2, P##b2, acc[2][2], 0, 0, 0); \
    acc[2][3] = __builtin_amdgcn_mfma_f32_16x16x32_f16(P##a2, P##b3, acc[2][3], 0, 0, 0); \
    acc[3][0] = __builtin_amdgcn_mfma_f32_16x16x32_f16(P##a3, P##b0, acc[3][0], 0, 0, 0); \
    acc[3][1] = __builtin_amdgcn_mfma_f32_16x16x32_f16(P##a3, P##b1, acc[3][1], 0, 0, 0); \
    acc[3][2] = __builtin_amdgcn_mfma_f32_16x16x32_f16(P##a3, P##b2, acc[3][2], 0, 0, 0); \
    acc[3][3] = __builtin_amdgcn_mfma_f32_16x16x32_f16(P##a3, P##b3, acc[3][3], 0, 0, 0);

    f16x8 Xa0, Xa1, Xa2, Xa3, Xb0, Xb1, Xb2, Xb3;
    f16x8 Ya0, Ya1, Ya2, Ya3, Yb0, Yb1, Yb2, Yb3;

#define LOAD_FRAGS(P, rb)                                                      \
    P##a0 = LDA(rb, 0); P##a1 = LDA(rb, 1); P##a2 = LDA(rb, 2); P##a3 = LDA(rb, 3); \
    P##b0 = LDB(rb, 0); P##b1 = LDB(rb, 1); P##b2 = LDB(rb, 2); P##b3 = LDB(rb, 3);

#define BODY(CUR, NXT, t)                                                      \
    {                                                                          \
        if ((t) + 1 < NT) { LOAD_FRAGS(NXT, (((t) + 1) & 3) * BUF) }           \
        if ((t) + 3 < NT) STAGE((((t) + 3) & 3) * BUF)                         \
        if ((t) + 1 < NT) {                                                    \
            asm volatile("s_waitcnt lgkmcnt(8)" ::: "memory");                 \
        } else {                                                               \
            asm volatile("s_waitcnt lgkmcnt(0)" ::: "memory");                 \
        }                                                                      \
        __builtin_amdgcn_sched_barrier(0);                                     \
        __builtin_amdgcn_s_setprio(1);                                         \
        MFMA_ALL(CUR)                                                          \
        __builtin_amdgcn_s_setprio(0);                                         \
        if ((t) + 3 < NT) {                                                    \
            asm volatile("s_waitcnt vmcnt(3)" ::: "memory");                   \
        } else {                                                               \
            asm volatile("s_waitcnt vmcnt(0)" ::: "memory");                   \
        }                                                                      \
        __builtin_amdgcn_s_barrier();                                          \
        __builtin_amdgcn_sched_barrier(0);                                     \
    }

    // ---- prologue: stage tiles 0,1,2; wait so tiles 0,1 complete (own);
    // barrier publishes; preload frags(tile 0) into X.
    STAGE(0 * BUF)
    STAGE(1 * BUF)
    STAGE(2 * BUF)
    asm volatile("s_waitcnt vmcnt(3)" ::: "memory");
    __builtin_amdgcn_s_barrier();
    __builtin_amdgcn_sched_barrier(0);
    LOAD_FRAGS(X, 0)

    for (int t = 0; t < NT; t += 2) {
        BODY(X, Y, t)
        BODY(Y, X, t + 1)
    }
#undef BODY
#undef LOAD_FRAGS
#undef LDA
#undef LDB
#undef MFMA_ALL
#undef STAGE

    // ---- epilogue: C/D layout col=lane&15, row=(lane>>4)*4+j ----
    const int crow0 = tm * BM + wm * 64 + ((lane >> 4) << 2);
    const int ccol0 = tn * BN + wn * 64 + (lane & 15);
    if constexpr (QUANT) {
        float c[16];
#pragma unroll
        for (int i = 0; i < 16; i++) c[i] = cb16[i];
        unsigned short* O = (unsigned short*)Cout;
#pragma unroll
        for (int m = 0; m < 4; m++)
#pragma unroll
            for (int n = 0; n < 4; n++)
#pragma unroll
                for (int j = 0; j < 4; j++) {
                    const float yn = acc[m][n][j] * 64.0f;
                    float v = c[0];
#pragma unroll
                    for (int i = 0; i < 15; i++) {
                        const float bnd = 0.5f * (c[i] + c[i + 1]);
                        v = (yn > bnd) ? c[i + 1] : v;
                    }
                    O[(size_t)(crow0 + m * 16 + j) * 4096 + ccol0 + n * 16] =
                        f2h(v * 0.015625f);
                }
    } else {
        float* O = (float*)Cout;
#pragma unroll
        for (int m = 0; m < 4; m++)
#pragma unroll
            for (int n = 0; n < 4; n++)
#pragma unroll
                for (int j = 0; j < 4; j++)
                    O[(size_t)(crow0 + m * 16 + j) * 4096 + ccol0 + n * 16] =
                        acc[m][n][j];
    }
}

extern "C" void kernel_launch(void* const* d_in, const int* in_sizes, int n_in,
                              void* d_out, int out_size, void* d_ws,
                              size_t ws_size, hipStream_t stream) {
    const float* x = (const float*)d_in[0];
    const float* rot = (const float*)d_in[1];
    const float* cb = (const float*)d_in[2];
    float* out = (float*)d_out;

    unsigned short* Xh = (unsigned short*)d_ws;
    unsigned short* Rh = Xh + (size_t)2048 * 4096;
    unsigned short* Rt = Rh + (size_t)4096 * 4096;
    unsigned short* Yh = Rt + (size_t)4096 * 4096;

    (void)hipFuncSetAttribute(
        reinterpret_cast<const void*>(&gemm_nt_kernel<true>),
        hipFuncAttributeMaxDynamicSharedMemorySize, LDS_DYN);
    (void)hipFuncSetAttribute(
        reinterpret_cast<const void*>(&gemm_nt_kernel<false>),
        hipFuncAttributeMaxDynamicSharedMemorySize, LDS_DYN);

    convert_x_kernel<<<8192, 256, 0, stream>>>(x, Xh);
    conv_rot_kernel<<<dim3(64, 64), 256, 0, stream>>>(rot, Rh, Rt);
    // y = x @ R^T : NT GEMM, Bt = Rh
    gemm_nt_kernel<true><<<256, 512, LDS_DYN, stream>>>(Xh, Rh, (void*)Yh, cb);
    // x_hat = y_hat @ R = y_hat @ (R^T)^T : NT GEMM, Bt = Rt
    gemm_nt_kernel<false><<<256, 512, LDS_DYN, stream>>>(Yh, Rt, (void*)out, nullptr);
}